// Round 6
// baseline (530.278 us; speedup 1.0000x reference)
//
#include <hip/hip_runtime.h>

#define MM 1024
#define NE 100000
#define KD 256
#define NT 782      // ceil(NE/128)  (fallback path)
#define NT2 391     // ceil(NE/256)
#define MT2 16      // 1024/64
#define NGRP2 64
#define PSTRIDE 784

typedef __attribute__((ext_vector_type(8))) short bf16x8;
typedef __attribute__((ext_vector_type(4))) float f32x4;
typedef __attribute__((ext_vector_type(4))) short short4v;

// ws layout (bytes):
//   [0, 524288)            hr bf16      1024*256*2
//   [524288, 528384)       hr_sq f32    1024
//   [528384, 928384)       ent_sq f32   100000
//   [1048576, 7471104)     argmax partials u64 [1024][784]
//   [8388608, +51.2MB)     ent bf16     100000*256*2   (tier A only)
#define WS_HRSQ   524288
#define WS_ENTSQ  528384
#define WS_PART   1048576
#define WS_ENTB   8388608
#define WS_NEED   (WS_ENTB + (size_t)NE * KD * 2)

#define AS1 __attribute__((address_space(1)))
#define AS3 __attribute__((address_space(3)))

__device__ __forceinline__ void gld_lds16(const void* g, void* l) {
    __builtin_amdgcn_global_load_lds((const AS1 unsigned int*)g,
                                     (AS3 unsigned int*)l, 16, 0, 0);
}

__device__ __forceinline__ unsigned short f2bf(float f) {
    union { float f; unsigned int u; } v; v.f = f;
    unsigned int u = v.u;
    return (unsigned short)((u + 0x7FFFu + ((u >> 16) & 1u)) >> 16);
}

__device__ __forceinline__ bf16x8 pack8(float4 a, float4 b) {
    bf16x8 t;
    t[0] = (short)f2bf(a.x); t[1] = (short)f2bf(a.y);
    t[2] = (short)f2bf(a.z); t[3] = (short)f2bf(a.w);
    t[4] = (short)f2bf(b.x); t[5] = (short)f2bf(b.y);
    t[6] = (short)f2bf(b.z); t[7] = (short)f2bf(b.w);
    return t;
}

// monotonic pack: bigger score -> bigger key; ties -> smaller col wins
__device__ __forceinline__ unsigned long long packkey(float s, int col) {
    unsigned int u = __float_as_uint(s);
    unsigned int key = u ^ ((unsigned int)((int)u >> 31) | 0x80000000u);
    return ((unsigned long long)key << 32) | (unsigned int)(~col);
}

// ---- prep: hr = E[head] + R[rel] -> bf16; hr_sq ----
__global__ __launch_bounds__(64) void prep_kernel(const int* __restrict__ q,
                                                  const float* __restrict__ ent,
                                                  const float* __restrict__ rel,
                                                  unsigned short* __restrict__ hrb,
                                                  float* __restrict__ hrsq) {
    int b = blockIdx.x;
    int lane = threadIdx.x;
    int head = q[b * 3 + 0];
    int r    = q[b * 3 + 1];
    float4 e  = ((const float4*)(ent + (size_t)head * KD))[lane];
    float4 rv = ((const float4*)(rel + (size_t)r * KD))[lane];
    float4 h; h.x = e.x + rv.x; h.y = e.y + rv.y; h.z = e.z + rv.z; h.w = e.w + rv.w;
    short4v hv;
    hv[0] = (short)f2bf(h.x); hv[1] = (short)f2bf(h.y);
    hv[2] = (short)f2bf(h.z); hv[3] = (short)f2bf(h.w);
    *(short4v*)(hrb + (size_t)b * KD + lane * 4) = hv;
    float sq = h.x * h.x + h.y * h.y + h.z * h.z + h.w * h.w;
    #pragma unroll
    for (int off = 32; off > 0; off >>= 1) sq += __shfl_down(sq, off, 64);
    if (lane == 0) hrsq[b] = sq;
}

// ---- fused: ent f32 -> bf16 + ent_sq ----
__global__ __launch_bounds__(256) void conv_entsq_kernel(const float* __restrict__ ent,
                                                         unsigned short* __restrict__ entb,
                                                         float* __restrict__ entsq) {
    int gw   = (blockIdx.x * 256 + threadIdx.x) >> 6;
    int lane = threadIdx.x & 63;
    int row  = gw * 2 + (lane >> 5);
    if (row >= NE) return;
    const float4* src = (const float4*)(ent + (size_t)row * KD) + (lane & 31) * 2;
    float4 a = src[0], b = src[1];
    *(bf16x8*)(entb + (size_t)row * KD + (lane & 31) * 8) = pack8(a, b);
    float s = a.x * a.x + a.y * a.y + a.z * a.z + a.w * a.w
            + b.x * b.x + b.y * b.y + b.z * b.z + b.w * b.w;
    #pragma unroll
    for (int off = 16; off > 0; off >>= 1) s += __shfl_xor(s, off, 64);
    if ((lane & 31) == 0) entsq[row] = s;
}

// ---- ent_sq only (fallback path) ----
__global__ __launch_bounds__(256) void entsq_kernel(const float* __restrict__ ent,
                                                    float* __restrict__ entsq) {
    int w = threadIdx.x >> 6, lane = threadIdx.x & 63;
    int n = blockIdx.x * 4 + w;
    if (n >= NE) return;
    float4 v = ((const float4*)(ent + (size_t)n * KD))[lane];
    float s = v.x * v.x + v.y * v.y + v.z * v.z + v.w * v.w;
    #pragma unroll
    for (int off = 32; off > 0; off >>= 1) s += __shfl_down(s, off, 64);
    if (lane == 0) entsq[n] = s;
}

// ---- GEMM v6: persistent 64x256 blocks, 4 waves side-by-side in n.
//      A panel (32KB) in LDS -> 4 blocks/CU; consecutive n-tiles per block
//      for write locality; barrier-free loop; register argmax. ----
__global__ __launch_bounds__(256, 4) void gemm_v6(const unsigned short* __restrict__ hrb,
                                                  const unsigned short* __restrict__ entb,
                                                  const float* __restrict__ hrsq,
                                                  const float* __restrict__ entsq,
                                                  float* __restrict__ out,
                                                  unsigned long long* __restrict__ part) {
    __shared__ __align__(16) char As[64 * 512];       // 32 KB swizzled bf16 A panel
    __shared__ unsigned long long lds_best[4][64];

    const int bid   = blockIdx.x;
    const int mtile = bid & 15;
    const int g     = bid >> 4;       // n-group: consecutive tiles
    const int m0    = mtile * 64;

    const int tid  = threadIdx.x;
    const int lane = tid & 63;
    const int wid  = tid >> 6;
    const int wc   = wid;             // wave column 0..3 (64 cols each)
    const int lr = lane & 15;
    const int lg = lane >> 4;
    const int lk = lg * 8;            // k elem offset of fragment slice

    // ---- stage A panel (swizzled source -> linear LDS dest), once ----
    {
        const char* hb = (const char*)hrb;
        #pragma unroll
        for (int i = 0; i < 8; ++i) {
            int L = i * 4096 + wid * 1024 + lane * 16;
            int G = L ^ (((L >> 9) & 7) << 4);
            int row = m0 + (L >> 9);
            const void* src = hb + (size_t)row * 512 + (G & 511);
            void* dst = As + i * 4096 + wid * 1024;   // wave-uniform base
            gld_lds16(src, dst);
        }
    }

    // ---- per-block row constants ----
    unsigned rowIdx[4][4];
    float    hq[4][4];
    #pragma unroll
    for (int mm = 0; mm < 4; ++mm)
        #pragma unroll
        for (int j = 0; j < 4; ++j) {
            int rg = m0 + mm * 16 + lg * 4 + j;
            rowIdx[mm][j] = (unsigned)rg * (unsigned)NE;
            hq[mm][j] = hrsq[rg];
        }

    float bestf[4][4];
    int   bestc[4][4];
    #pragma unroll
    for (int mm = 0; mm < 4; ++mm)
        #pragma unroll
        for (int j = 0; j < 4; ++j) { bestf[mm][j] = -3.4e38f; bestc[mm][j] = 0; }

    __syncthreads();   // A panel ready (drains staging)

    // ---- persistent loop over CONSECUTIVE n-tiles: NO barriers inside ----
    const int tstart = (g * NT2) / NGRP2;
    const int tend   = ((g + 1) * NT2) / NGRP2;
    for (int t = tstart; t < tend; ++t) {
        const unsigned short* bP[4];
        int cg[4]; bool cv[4]; float eq[4];
        #pragma unroll
        for (int nn = 0; nn < 4; ++nn) {
            int nr = t * 256 + wc * 64 + nn * 16 + lr;
            cg[nn] = nr;
            cv[nn] = nr < NE;
            int nrc = cv[nn] ? nr : (NE - 1);
            bP[nn] = entb + (size_t)nrc * KD + lk;
            eq[nn] = entsq[nrc];
        }

        f32x4 acc[4][4];
        #pragma unroll
        for (int mm = 0; mm < 4; ++mm)
            #pragma unroll
            for (int nn = 0; nn < 4; ++nn)
                acc[mm][nn] = (f32x4){0.f, 0.f, 0.f, 0.f};

        #pragma unroll
        for (int ks = 0; ks < 8; ++ks) {
            bf16x8 bfr[4];
            #pragma unroll
            for (int nn = 0; nn < 4; ++nn)
                bfr[nn] = *(const bf16x8*)(bP[nn] + ks * 32);
            bf16x8 af[4];
            #pragma unroll
            for (int mm = 0; mm < 4; ++mm) {
                int r = mm * 16 + lr;
                int byte = r * 512 + ((ks * 64 + lg * 16) ^ ((r & 7) << 4));
                af[mm] = *(const bf16x8*)((const char*)As + byte);
            }
            #pragma unroll
            for (int mm = 0; mm < 4; ++mm)
                #pragma unroll
                for (int nn = 0; nn < 4; ++nn)
                    acc[mm][nn] = __builtin_amdgcn_mfma_f32_16x16x32_bf16(af[mm], bfr[nn], acc[mm][nn], 0, 0, 0);
        }

        // epilogue: scores + in-register argmax
        #pragma unroll
        for (int mm = 0; mm < 4; ++mm) {
            #pragma unroll
            for (int j = 0; j < 4; ++j) {
                float hqe = hq[mm][j];
                unsigned ro = rowIdx[mm][j];
                #pragma unroll
                for (int nn = 0; nn < 4; ++nn) {
                    if (cv[nn]) {
                        float s = 2.0f * acc[mm][nn][j] - hqe - eq[nn];
                        out[ro + (unsigned)cg[nn]] = s;
                        if (s > bestf[mm][j]) { bestf[mm][j] = s; bestc[mm][j] = cg[nn]; }
                    }
                }
            }
        }
    }

    // ---- block-end argmax reduce ----
    unsigned long long rowbest[4][4];
    #pragma unroll
    for (int mm = 0; mm < 4; ++mm)
        #pragma unroll
        for (int j = 0; j < 4; ++j) {
            unsigned long long best = packkey(bestf[mm][j], bestc[mm][j]);
            #pragma unroll
            for (int off = 8; off > 0; off >>= 1) {
                unsigned long long o =
                    (unsigned long long)__shfl_xor((long long)best, off, 16);
                best = (o > best) ? o : best;
            }
            rowbest[mm][j] = best;
        }
    if (lr == 0) {
        #pragma unroll
        for (int mm = 0; mm < 4; ++mm)
            #pragma unroll
            for (int j = 0; j < 4; ++j)
                lds_best[wc][mm * 16 + lg * 4 + j] = rowbest[mm][j];
    }
    __syncthreads();
    if (tid < 64) {
        unsigned long long b0 = lds_best[0][tid];
        unsigned long long b1 = lds_best[1][tid];
        unsigned long long b2 = lds_best[2][tid];
        unsigned long long b3 = lds_best[3][tid];
        unsigned long long best = b0 > b1 ? b0 : b1;
        if (b2 > best) best = b2;
        if (b3 > best) best = b3;
        part[(size_t)(m0 + tid) * PSTRIDE + g] = best;
    }
}

// ---- fallback GEMM (B from f32 directly), atomic-free partials ----
__global__ __launch_bounds__(256, 3) void gemm_direct_f32(const unsigned short* __restrict__ hrb,
                                                          const float* __restrict__ entf,
                                                          const float* __restrict__ hrsq,
                                                          const float* __restrict__ entsq,
                                                          float* __restrict__ out,
                                                          unsigned long long* __restrict__ part) {
    __shared__ unsigned long long lds_best[2][128];
    const int bid  = blockIdx.x;
    const int wgid = (bid & 7) * NT + (bid >> 3);
    const int mt = wgid & 7, nt = wgid >> 3;
    const int m0 = mt * 128, n0 = nt * 128;
    const int tid  = threadIdx.x;
    const int lane = tid & 63;
    const int wid  = tid >> 6;
    const int wr = wid >> 1, wc = wid & 1;
    const int lr = lane & 15;
    const int lk = (lane >> 4) * 8;

    const unsigned short* aP[4];
    const float*          bPf[4];
    int  cg[4];
    bool cv[4];
    #pragma unroll
    for (int i = 0; i < 4; ++i) {
        int ar = m0 + wr * 64 + i * 16 + lr;
        aP[i] = hrb + (size_t)ar * KD + lk;
        int nr = n0 + wc * 64 + i * 16 + lr;
        cg[i] = nr; cv[i] = nr < NE;
        bPf[i] = entf + (size_t)(cv[i] ? nr : 0) * KD + lk;
    }

    f32x4 acc[4][4];
    #pragma unroll
    for (int m = 0; m < 4; ++m)
        #pragma unroll
        for (int n = 0; n < 4; ++n)
            acc[m][n] = (f32x4){0.f, 0.f, 0.f, 0.f};

    #pragma unroll
    for (int ks = 0; ks < KD / 32; ++ks) {
        bf16x8 af[4], bfr[4];
        #pragma unroll
        for (int i = 0; i < 4; ++i)
            af[i] = *(const bf16x8*)(aP[i] + ks * 32);
        #pragma unroll
        for (int i = 0; i < 4; ++i) {
            const float4* p = (const float4*)(bPf[i] + ks * 32);
            bfr[i] = pack8(p[0], p[1]);
        }
        #pragma unroll
        for (int m = 0; m < 4; ++m)
            #pragma unroll
            for (int n = 0; n < 4; ++n)
                acc[m][n] = __builtin_amdgcn_mfma_f32_16x16x32_bf16(af[m], bfr[n], acc[m][n], 0, 0, 0);
    }

    float eq[4];
    #pragma unroll
    for (int n = 0; n < 4; ++n) eq[n] = cv[n] ? entsq[cg[n]] : 0.f;

    unsigned long long rowbest[4][4];
    #pragma unroll
    for (int m = 0; m < 4; ++m) {
        #pragma unroll
        for (int j = 0; j < 4; ++j) {
            int rg = m0 + wr * 64 + m * 16 + ((lane >> 4) << 2) + j;
            float hqv = hrsq[rg];
            size_t ro = (size_t)rg * NE;
            unsigned long long best = 0ull;
            #pragma unroll
            for (int n = 0; n < 4; ++n) {
                if (cv[n]) {
                    float s = 2.0f * acc[m][n][j] - hqv - eq[n];
                    out[ro + cg[n]] = s;
                    unsigned long long k64 = packkey(s, cg[n]);
                    best = (k64 > best) ? k64 : best;
                }
            }
            #pragma unroll
            for (int off = 8; off > 0; off >>= 1) {
                unsigned long long o =
                    (unsigned long long)__shfl_xor((long long)best, off, 16);
                best = (o > best) ? o : best;
            }
            rowbest[m][j] = best;
        }
    }
    if (lr == 0) {
        int gg = lane >> 4;
        #pragma unroll
        for (int m = 0; m < 4; ++m)
            #pragma unroll
            for (int j = 0; j < 4; ++j)
                lds_best[wc][wr * 64 + m * 16 + gg * 4 + j] = rowbest[m][j];
    }
    __syncthreads();
    if (tid < 128) {
        unsigned long long a = lds_best[0][tid];
        unsigned long long b = lds_best[1][tid];
        unsigned long long best = a > b ? a : b;
        part[(size_t)(m0 + tid) * PSTRIDE + nt] = best;
    }
}

// ---- reduce: per row, max over NP partials -> prediction ----
__global__ __launch_bounds__(256) void reduce_kernel(const unsigned long long* __restrict__ part,
                                                     float* __restrict__ pred, int np) {
    __shared__ unsigned long long sb[256];
    int row = blockIdx.x;
    int tid = threadIdx.x;
    const unsigned long long* base = part + (size_t)row * PSTRIDE;
    unsigned long long best = 0ull;
    for (int i = tid; i < np; i += 256) {
        unsigned long long v = base[i];
        best = v > best ? v : best;
    }
    sb[tid] = best;
    __syncthreads();
    #pragma unroll
    for (int s = 128; s > 0; s >>= 1) {
        if (tid < s) {
            unsigned long long o = sb[tid + s];
            if (o > sb[tid]) sb[tid] = o;
        }
        __syncthreads();
    }
    if (tid == 0) {
        unsigned int ic = (unsigned int)(sb[0] & 0xFFFFFFFFull);
        pred[row] = (float)(~ic);
    }
}

extern "C" void kernel_launch(void* const* d_in, const int* in_sizes, int n_in,
                              void* d_out, int out_size, void* d_ws, size_t ws_size,
                              hipStream_t stream) {
    const int*   q   = (const int*)d_in[0];
    const float* ent = (const float*)d_in[1];
    const float* rel = (const float*)d_in[2];
    float* out = (float*)d_out;
    char*  ws  = (char*)d_ws;

    unsigned short*     hrb   = (unsigned short*)ws;
    float*              hrsq  = (float*)(ws + WS_HRSQ);
    float*              entsq = (float*)(ws + WS_ENTSQ);
    unsigned long long* part  = (unsigned long long*)(ws + WS_PART);
    unsigned short*     entb  = (unsigned short*)(ws + WS_ENTB);
    float* pred = out + (size_t)MM * NE;

    prep_kernel<<<MM, 64, 0, stream>>>(q, ent, rel, hrb, hrsq);

    if (ws_size >= WS_NEED) {
        conv_entsq_kernel<<<12500, 256, 0, stream>>>(ent, entb, entsq);
        gemm_v6<<<MT2 * NGRP2, 256, 0, stream>>>(hrb, entb, hrsq, entsq, out, part);
        reduce_kernel<<<MM, 256, 0, stream>>>(part, pred, NGRP2);
    } else {
        entsq_kernel<<<(NE + 3) / 4, 256, 0, stream>>>(ent, entsq);
        gemm_direct_f32<<<8 * NT, 256, 0, stream>>>(hrb, ent, hrsq, entsq, out, part);
        reduce_kernel<<<MM, 256, 0, stream>>>(part, pred, NT);
    }
}

// Round 7
// 295.302 us; speedup vs baseline: 1.7957x; 1.7957x over previous
//
#include <hip/hip_runtime.h>

#define MM 1024
#define NE 100000
#define KD 256
#define NT 782      // ceil(NE/128)
#define NGRP 64     // n-tile groups (persistent, stride walk)
#define PSTRIDE 784

typedef __attribute__((ext_vector_type(8))) short bf16x8;
typedef __attribute__((ext_vector_type(4))) float f32x4;
typedef __attribute__((ext_vector_type(4))) short short4v;

// ws layout (bytes):
//   [0, 524288)            hr bf16      1024*256*2
//   [524288, 528384)       hr_sq f32    1024
//   [528384, 928384)       ent_sq f32   100000
//   [1048576, 7471104)     argmax partials u64 [1024][784]
//   [8388608, +51.2MB)     ent bf16     100000*256*2   (tier A only)
#define WS_HRSQ   524288
#define WS_ENTSQ  528384
#define WS_PART   1048576
#define WS_ENTB   8388608
#define WS_NEED   (WS_ENTB + (size_t)NE * KD * 2)

#define AS1 __attribute__((address_space(1)))
#define AS3 __attribute__((address_space(3)))

__device__ __forceinline__ void gld_lds16(const void* g, void* l) {
    __builtin_amdgcn_global_load_lds((const AS1 unsigned int*)g,
                                     (AS3 unsigned int*)l, 16, 0, 0);
}

__device__ __forceinline__ unsigned short f2bf(float f) {
    union { float f; unsigned int u; } v; v.f = f;
    unsigned int u = v.u;
    return (unsigned short)((u + 0x7FFFu + ((u >> 16) & 1u)) >> 16);
}

__device__ __forceinline__ bf16x8 pack8(float4 a, float4 b) {
    bf16x8 t;
    t[0] = (short)f2bf(a.x); t[1] = (short)f2bf(a.y);
    t[2] = (short)f2bf(a.z); t[3] = (short)f2bf(a.w);
    t[4] = (short)f2bf(b.x); t[5] = (short)f2bf(b.y);
    t[6] = (short)f2bf(b.z); t[7] = (short)f2bf(b.w);
    return t;
}

// monotonic pack: bigger score -> bigger key; ties -> smaller col wins
__device__ __forceinline__ unsigned long long packkey(float s, int col) {
    unsigned int u = __float_as_uint(s);
    unsigned int key = u ^ ((unsigned int)((int)u >> 31) | 0x80000000u);
    return ((unsigned long long)key << 32) | (unsigned int)(~col);
}

// ---- prep: hr = E[head] + R[rel] -> bf16; hr_sq ----
__global__ __launch_bounds__(64) void prep_kernel(const int* __restrict__ q,
                                                  const float* __restrict__ ent,
                                                  const float* __restrict__ rel,
                                                  unsigned short* __restrict__ hrb,
                                                  float* __restrict__ hrsq) {
    int b = blockIdx.x;
    int lane = threadIdx.x;
    int head = q[b * 3 + 0];
    int r    = q[b * 3 + 1];
    float4 e  = ((const float4*)(ent + (size_t)head * KD))[lane];
    float4 rv = ((const float4*)(rel + (size_t)r * KD))[lane];
    float4 h; h.x = e.x + rv.x; h.y = e.y + rv.y; h.z = e.z + rv.z; h.w = e.w + rv.w;
    short4v hv;
    hv[0] = (short)f2bf(h.x); hv[1] = (short)f2bf(h.y);
    hv[2] = (short)f2bf(h.z); hv[3] = (short)f2bf(h.w);
    *(short4v*)(hrb + (size_t)b * KD + lane * 4) = hv;
    float sq = h.x * h.x + h.y * h.y + h.z * h.z + h.w * h.w;
    #pragma unroll
    for (int off = 32; off > 0; off >>= 1) sq += __shfl_down(sq, off, 64);
    if (lane == 0) hrsq[b] = sq;
}

// ---- fused: ent f32 -> bf16 + ent_sq ----
__global__ __launch_bounds__(256) void conv_entsq_kernel(const float* __restrict__ ent,
                                                         unsigned short* __restrict__ entb,
                                                         float* __restrict__ entsq) {
    int gw   = (blockIdx.x * 256 + threadIdx.x) >> 6;
    int lane = threadIdx.x & 63;
    int row  = gw * 2 + (lane >> 5);
    if (row >= NE) return;
    const float4* src = (const float4*)(ent + (size_t)row * KD) + (lane & 31) * 2;
    float4 a = src[0], b = src[1];
    *(bf16x8*)(entb + (size_t)row * KD + (lane & 31) * 8) = pack8(a, b);
    float s = a.x * a.x + a.y * a.y + a.z * a.z + a.w * a.w
            + b.x * b.x + b.y * b.y + b.z * b.z + b.w * b.w;
    #pragma unroll
    for (int off = 16; off > 0; off >>= 1) s += __shfl_xor(s, off, 64);
    if ((lane & 31) == 0) entsq[row] = s;
}

// ---- ent_sq only (fallback path) ----
__global__ __launch_bounds__(256) void entsq_kernel(const float* __restrict__ ent,
                                                    float* __restrict__ entsq) {
    int w = threadIdx.x >> 6, lane = threadIdx.x & 63;
    int n = blockIdx.x * 4 + w;
    if (n >= NE) return;
    float4 v = ((const float4*)(ent + (size_t)n * KD))[lane];
    float s = v.x * v.x + v.y * v.y + v.z * v.z + v.w * v.w;
    #pragma unroll
    for (int off = 32; off > 0; off >>= 1) s += __shfl_down(s, off, 64);
    if (lane == 0) entsq[n] = s;
}

// ---- GEMM v7: R5's persistent schedule, SWAPPED MFMA operands.
//      A-operand = entity fragments (global), B-operand = hr panel (LDS).
//      D: row = entity (lg*4+j -> 4 consecutive), col = query (lr)
//      => f32x4 wide stores. Register argmax per query. ----
__global__ __launch_bounds__(256, 2) void gemm_v7(const unsigned short* __restrict__ hrb,
                                                  const unsigned short* __restrict__ entb,
                                                  const float* __restrict__ hrsq,
                                                  const float* __restrict__ entsq,
                                                  float* __restrict__ out,
                                                  unsigned long long* __restrict__ part) {
    __shared__ __align__(16) char Qs[128 * 512];      // 64 KB swizzled hr panel
    __shared__ unsigned long long lds_best[2][128];

    const int bid    = blockIdx.x;
    const int qpanel = bid & 7;       // 8 query panels of 128
    const int g      = bid >> 3;      // tile group: t = g, g+64, ...
    const int q0     = qpanel * 128;

    const int tid  = threadIdx.x;
    const int lane = tid & 63;
    const int wid  = tid >> 6;
    const int wq = wid >> 1;          // query half (0..1)
    const int we = wid & 1;           // entity half (0..1)
    const int lr = lane & 15;
    const int lg = lane >> 4;
    const int lk = lg * 8;            // k elem offset of fragment slice

    // ---- stage hr panel (swizzled source -> linear LDS dest), once ----
    {
        const char* hb = (const char*)hrb;
        #pragma unroll
        for (int i = 0; i < 16; ++i) {
            int L = i * 4096 + wid * 1024 + lane * 16;
            int G = L ^ (((L >> 9) & 7) << 4);
            int row = q0 + (L >> 9);
            const void* src = hb + (size_t)row * 512 + (G & 511);
            void* dst = Qs + i * 4096 + wid * 1024;   // wave-uniform base
            gld_lds16(src, dst);
        }
    }

    // ---- per-block query constants (hoisted) ----
    int   qg[4];
    float hq[4];
    unsigned qoff[4];
    #pragma unroll
    for (int nn = 0; nn < 4; ++nn) {
        qg[nn] = q0 + wq * 64 + nn * 16 + lr;
        hq[nn] = hrsq[qg[nn]];
        qoff[nn] = (unsigned)qg[nn] * (unsigned)NE;
    }

    float bestf[4];
    int   bestc[4];
    #pragma unroll
    for (int nn = 0; nn < 4; ++nn) { bestf[nn] = -3.4e38f; bestc[nn] = 0; }

    __syncthreads();   // hr panel ready (drains staging)

    // ---- persistent tile-strided loop (lock-step sharers): NO barriers ----
    for (int t = g; t < NT; t += NGRP) {
        const int e0 = t * 128 + we * 64;   // this wave's 64-entity strip

        // A-operand pointers: entity rows (lr selects row within fragment)
        const unsigned short* aP[4];
        #pragma unroll
        for (int mm = 0; mm < 4; ++mm) {
            int er = e0 + mm * 16 + lr;
            er = er < NE ? er : (NE - 1);
            aP[mm] = entb + (size_t)er * KD + lk;
        }

        f32x4 acc[4][4];   // [mm(entity)][nn(query)]
        #pragma unroll
        for (int mm = 0; mm < 4; ++mm)
            #pragma unroll
            for (int nn = 0; nn < 4; ++nn)
                acc[mm][nn] = (f32x4){0.f, 0.f, 0.f, 0.f};

        #pragma unroll
        for (int ks = 0; ks < 8; ++ks) {
            bf16x8 af[4];
            #pragma unroll
            for (int mm = 0; mm < 4; ++mm)
                af[mm] = *(const bf16x8*)(aP[mm] + ks * 32);
            bf16x8 qf[4];
            #pragma unroll
            for (int nn = 0; nn < 4; ++nn) {
                int r = wq * 64 + nn * 16 + lr;
                int byte = r * 512 + ((ks * 64 + lg * 16) ^ ((r & 7) << 4));
                qf[nn] = *(const bf16x8*)((const char*)Qs + byte);
            }
            #pragma unroll
            for (int mm = 0; mm < 4; ++mm)
                #pragma unroll
                for (int nn = 0; nn < 4; ++nn)
                    acc[mm][nn] = __builtin_amdgcn_mfma_f32_16x16x32_bf16(af[mm], qf[nn], acc[mm][nn], 0, 0, 0);
        }

        // ---- epilogue: wide f32x4 stores + register argmax ----
        #pragma unroll
        for (int mm = 0; mm < 4; ++mm) {
            const int eb = e0 + mm * 16 + lg * 4;   // 4 consecutive entities
            const bool ev = eb < NE;                 // NE%4==0 -> all-or-none
            const int ebc = ev ? eb : (NE - 4);
            const float4 eq = *(const float4*)(entsq + ebc);
            #pragma unroll
            for (int nn = 0; nn < 4; ++nn) {
                float4 sv;
                sv.x = 2.0f * acc[mm][nn][0] - hq[nn] - eq.x;
                sv.y = 2.0f * acc[mm][nn][1] - hq[nn] - eq.y;
                sv.z = 2.0f * acc[mm][nn][2] - hq[nn] - eq.z;
                sv.w = 2.0f * acc[mm][nn][3] - hq[nn] - eq.w;
                if (ev) {
                    *(float4*)(out + qoff[nn] + (unsigned)eb) = sv;
                    // argmax update (tie -> smaller col: strict > keeps earlier)
                    if (sv.x > bestf[nn]) { bestf[nn] = sv.x; bestc[nn] = eb; }
                    if (sv.y > bestf[nn]) { bestf[nn] = sv.y; bestc[nn] = eb + 1; }
                    if (sv.z > bestf[nn]) { bestf[nn] = sv.z; bestc[nn] = eb + 2; }
                    if (sv.w > bestf[nn]) { bestf[nn] = sv.w; bestc[nn] = eb + 3; }
                }
            }
        }
    }

    // ---- block-end argmax reduce: across lg (xor 16,32), LDS combine ----
    #pragma unroll
    for (int nn = 0; nn < 4; ++nn) {
        unsigned long long best = packkey(bestf[nn], bestc[nn]);
        #pragma unroll
        for (int off = 16; off <= 32; off <<= 1) {
            unsigned long long o =
                (unsigned long long)__shfl_xor((long long)best, off, 64);
            best = (o > best) ? o : best;
        }
        if (lg == 0)
            lds_best[we][wq * 64 + nn * 16 + lr] = best;
    }
    __syncthreads();
    if (tid < 128) {
        unsigned long long a = lds_best[0][tid];
        unsigned long long b = lds_best[1][tid];
        unsigned long long best = a > b ? a : b;
        part[(size_t)(q0 + tid) * PSTRIDE + g] = best;
    }
}

// ---- fallback GEMM (B from f32 directly), atomic-free partials ----
__global__ __launch_bounds__(256, 3) void gemm_direct_f32(const unsigned short* __restrict__ hrb,
                                                          const float* __restrict__ entf,
                                                          const float* __restrict__ hrsq,
                                                          const float* __restrict__ entsq,
                                                          float* __restrict__ out,
                                                          unsigned long long* __restrict__ part) {
    __shared__ unsigned long long lds_best[2][128];
    const int bid  = blockIdx.x;
    const int wgid = (bid & 7) * NT + (bid >> 3);
    const int mt = wgid & 7, nt = wgid >> 3;
    const int m0 = mt * 128, n0 = nt * 128;
    const int tid  = threadIdx.x;
    const int lane = tid & 63;
    const int wid  = tid >> 6;
    const int wr = wid >> 1, wc = wid & 1;
    const int lr = lane & 15;
    const int lk = (lane >> 4) * 8;

    const unsigned short* aP[4];
    const float*          bPf[4];
    int  cg[4];
    bool cv[4];
    #pragma unroll
    for (int i = 0; i < 4; ++i) {
        int ar = m0 + wr * 64 + i * 16 + lr;
        aP[i] = hrb + (size_t)ar * KD + lk;
        int nr = n0 + wc * 64 + i * 16 + lr;
        cg[i] = nr; cv[i] = nr < NE;
        bPf[i] = entf + (size_t)(cv[i] ? nr : 0) * KD + lk;
    }

    f32x4 acc[4][4];
    #pragma unroll
    for (int m = 0; m < 4; ++m)
        #pragma unroll
        for (int n = 0; n < 4; ++n)
            acc[m][n] = (f32x4){0.f, 0.f, 0.f, 0.f};

    #pragma unroll
    for (int ks = 0; ks < KD / 32; ++ks) {
        bf16x8 af[4], bfr[4];
        #pragma unroll
        for (int i = 0; i < 4; ++i)
            af[i] = *(const bf16x8*)(aP[i] + ks * 32);
        #pragma unroll
        for (int i = 0; i < 4; ++i) {
            const float4* p = (const float4*)(bPf[i] + ks * 32);
            bfr[i] = pack8(p[0], p[1]);
        }
        #pragma unroll
        for (int m = 0; m < 4; ++m)
            #pragma unroll
            for (int n = 0; n < 4; ++n)
                acc[m][n] = __builtin_amdgcn_mfma_f32_16x16x32_bf16(af[m], bfr[n], acc[m][n], 0, 0, 0);
    }

    float eq[4];
    #pragma unroll
    for (int n = 0; n < 4; ++n) eq[n] = cv[n] ? entsq[cg[n]] : 0.f;

    unsigned long long rowbest[4][4];
    #pragma unroll
    for (int m = 0; m < 4; ++m) {
        #pragma unroll
        for (int j = 0; j < 4; ++j) {
            int rg = m0 + wr * 64 + m * 16 + ((lane >> 4) << 2) + j;
            float hqv = hrsq[rg];
            size_t ro = (size_t)rg * NE;
            unsigned long long best = 0ull;
            #pragma unroll
            for (int n = 0; n < 4; ++n) {
                if (cv[n]) {
                    float s = 2.0f * acc[m][n][j] - hqv - eq[n];
                    out[ro + cg[n]] = s;
                    unsigned long long k64 = packkey(s, cg[n]);
                    best = (k64 > best) ? k64 : best;
                }
            }
            #pragma unroll
            for (int off = 8; off > 0; off >>= 1) {
                unsigned long long o =
                    (unsigned long long)__shfl_xor((long long)best, off, 16);
                best = (o > best) ? o : best;
            }
            rowbest[m][j] = best;
        }
    }
    if (lr == 0) {
        int gg = lane >> 4;
        #pragma unroll
        for (int m = 0; m < 4; ++m)
            #pragma unroll
            for (int j = 0; j < 4; ++j)
                lds_best[wc][wr * 64 + m * 16 + gg * 4 + j] = rowbest[m][j];
    }
    __syncthreads();
    if (tid < 128) {
        unsigned long long a = lds_best[0][tid];
        unsigned long long b = lds_best[1][tid];
        unsigned long long best = a > b ? a : b;
        part[(size_t)(m0 + tid) * PSTRIDE + nt] = best;
    }
}

// ---- reduce: per row, max over NP partials -> prediction ----
__global__ __launch_bounds__(256) void reduce_kernel(const unsigned long long* __restrict__ part,
                                                     float* __restrict__ pred, int np) {
    __shared__ unsigned long long sb[256];
    int row = blockIdx.x;
    int tid = threadIdx.x;
    const unsigned long long* base = part + (size_t)row * PSTRIDE;
    unsigned long long best = 0ull;
    for (int i = tid; i < np; i += 256) {
        unsigned long long v = base[i];
        best = v > best ? v : best;
    }
    sb[tid] = best;
    __syncthreads();
    #pragma unroll
    for (int s = 128; s > 0; s >>= 1) {
        if (tid < s) {
            unsigned long long o = sb[tid + s];
            if (o > sb[tid]) sb[tid] = o;
        }
        __syncthreads();
    }
    if (tid == 0) {
        unsigned int ic = (unsigned int)(sb[0] & 0xFFFFFFFFull);
        pred[row] = (float)(~ic);
    }
}

extern "C" void kernel_launch(void* const* d_in, const int* in_sizes, int n_in,
                              void* d_out, int out_size, void* d_ws, size_t ws_size,
                              hipStream_t stream) {
    const int*   q   = (const int*)d_in[0];
    const float* ent = (const float*)d_in[1];
    const float* rel = (const float*)d_in[2];
    float* out = (float*)d_out;
    char*  ws  = (char*)d_ws;

    unsigned short*     hrb   = (unsigned short*)ws;
    float*              hrsq  = (float*)(ws + WS_HRSQ);
    float*              entsq = (float*)(ws + WS_ENTSQ);
    unsigned long long* part  = (unsigned long long*)(ws + WS_PART);
    unsigned short*     entb  = (unsigned short*)(ws + WS_ENTB);
    float* pred = out + (size_t)MM * NE;

    prep_kernel<<<MM, 64, 0, stream>>>(q, ent, rel, hrb, hrsq);

    if (ws_size >= WS_NEED) {
        conv_entsq_kernel<<<12500, 256, 0, stream>>>(ent, entb, entsq);
        gemm_v7<<<8 * NGRP, 256, 0, stream>>>(hrb, entb, hrsq, entsq, out, part);
        reduce_kernel<<<MM, 256, 0, stream>>>(part, pred, NGRP);
    } else {
        entsq_kernel<<<(NE + 3) / 4, 256, 0, stream>>>(ent, entsq);
        gemm_direct_f32<<<8 * NT, 256, 0, stream>>>(hrb, ent, hrsq, entsq, out, part);
        reduce_kernel<<<MM, 256, 0, stream>>>(part, pred, NT);
    }
}